// Round 2
// baseline (208.673 us; speedup 1.0000x reference)
//
#include <hip/hip_runtime.h>

// Problem constants (fixed by setup_inputs)
#define B  32
#define H  56
#define W  56
#define C  256
#define CR 64
#define S  (H * W)              // 3136 spatial positions
#define CHUNKS 49               // spatial chunks per batch
#define ROWS_PER_CHUNK (S / CHUNKS)   // 64 rows -> 16 float4-iters/thread
#define C4 (C / 4)              // 64 float4 channel groups

typedef float floatx4 __attribute__((ext_vector_type(4)));

// ---------------------------------------------------------------------------
// Kernel 1: partial global-average-pool sums.
// Grid: (CHUNKS, B) x 256. Thread t covers channel-group (t&63), spatial
// sub-offset (t>>6) -> fully coalesced 256-lane x 16B loads. 16 fixed iters.
// Normal (caching) loads on purpose: x must be L3-resident for kernel 2.
// NOTE (R4 lesson): no device-scope fences/atomics — per-block agent fences
// cost ~190 us of L2 writeback stalls on gfx950.
// ---------------------------------------------------------------------------
__global__ void gap_kernel(const float* __restrict__ x, float* __restrict__ part) {
    const int chunk = blockIdx.x;
    const int b     = blockIdx.y;
    const int t  = threadIdx.x;       // 0..255
    const int cg = t & 63;            // channel float4-group
    const int so = t >> 6;            // spatial sub-offset 0..3

    const float4* x4 = (const float4*)x
                     + (size_t)b * (S * C4)
                     + (size_t)(chunk * ROWS_PER_CHUNK) * C4
                     + (size_t)so * C4 + cg;

    float4 acc = make_float4(0.f, 0.f, 0.f, 0.f);
    #pragma unroll
    for (int i = 0; i < ROWS_PER_CHUNK / 4; ++i) {   // 16 iterations
        float4 v = x4[(size_t)i * 4 * C4];
        acc.x += v.x; acc.y += v.y; acc.z += v.z; acc.w += v.w;
    }

    __shared__ float4 sdata[256];
    sdata[t] = acc;
    __syncthreads();

    if (t < 64) {
        float4 a = sdata[t], b2 = sdata[t + 64], c2 = sdata[t + 128], d2 = sdata[t + 192];
        float4 tot;
        tot.x = a.x + b2.x + c2.x + d2.x;
        tot.y = a.y + b2.y + c2.y + d2.y;
        tot.z = a.z + b2.z + c2.z + d2.z;
        tot.w = a.w + b2.w + c2.w + d2.w;
        ((float4*)part)[(size_t)(b * CHUNKS + chunk) * 64 + t] = tot;
    }
}

// ---------------------------------------------------------------------------
// Kernel 2 (R1 fusion): per-block recompute of the gate, then scale.
// Grid: (CHUNKS, B) x 256 — same shape as gap, 16 float4/thread, so the
// gate redundancy is only 49x per batch (78 MB of L2/L3-hot part reads
// aggregate, ~3 us) instead of a separate 32-block kernel (~5 us serial +
// launch boundary).
// Gate phase: mean(part) -> FC1 (4-way c-split over 256 thr) -> relu6 ->
// FC2 -> hsigmoid -> gs[] in LDS. Scale phase: identical addressing to gap.
// Stores are NORMAL (not NT): x+out = 205.6 MB < 256 MB L3 (R0 lesson).
// ---------------------------------------------------------------------------
__global__ void gate_scale_kernel(const float* __restrict__ x,
                                  const float* __restrict__ part,
                                  const float* __restrict__ w1,
                                  const float* __restrict__ w2,
                                  float* __restrict__ out) {
    const int chunk = blockIdx.x;
    const int b     = blockIdx.y;
    const int t  = threadIdx.x;       // 0..255

    __shared__ float ss[C];
    __shared__ float s1p[4][CR];
    __shared__ float s1s[CR];
    __shared__ float gs[C];

    // ---- mean over chunks (part is L2/L3-hot, 1.6 MB total) ----
    float sum = 0.f;
    #pragma unroll 7
    for (int ch = 0; ch < CHUNKS; ++ch)
        sum += part[(size_t)(b * CHUNKS + ch) * C + t];   // coalesced over t
    ss[t] = sum * (1.0f / (float)S);
    __syncthreads();

    // ---- FC1: all 256 threads, 4 c-quarters x 64 r ----
    {
        const int r = t & 63;
        const int q = t >> 6;
        float a = 0.f;
        #pragma unroll 8
        for (int c = 0; c < C / 4; ++c)
            a += ss[q * 64 + c] * w1[(q * 64 + c) * CR + r];  // coalesced over r
        s1p[q][r] = a;
    }
    __syncthreads();

    if (t < CR) {
        float v = s1p[0][t] + s1p[1][t] + s1p[2][t] + s1p[3][t];
        s1s[t] = fminf(fmaxf(v, 0.f), 6.f);                   // ReLU6
    }
    __syncthreads();

    // ---- FC2 + hsigmoid -> gs[t] ----
    {
        float s2 = 0.f;
        #pragma unroll 8
        for (int r = 0; r < CR; ++r)
            s2 += s1s[r] * w2[r * C + t];         // w2: [CR, C], coalesced over t
        gs[t] = fminf(fmaxf(s2 + 3.f, 0.f), 6.f) * (1.f / 6.f);
    }
    __syncthreads();

    // ---- scale: same addressing as gap (fully coalesced, L3-hot x) ----
    const int cg = t & 63;
    const int so = t >> 6;
    const size_t base = (size_t)b * (S * C4)
                      + (size_t)(chunk * ROWS_PER_CHUNK) * C4
                      + (size_t)so * C4 + cg;
    const floatx4* x4 = (const floatx4*)x + base;
    floatx4*       o4 = (floatx4*)out + base;
    const float4 gv = ((const float4*)gs)[cg];

    #pragma unroll
    for (int i = 0; i < ROWS_PER_CHUNK / 4; ++i) {   // 16 iterations
        floatx4 xv = x4[(size_t)i * 4 * C4];
        floatx4 o;
        o.x = xv.x * gv.x;
        o.y = xv.y * gv.y;
        o.z = xv.z * gv.z;
        o.w = xv.w * gv.w;
        o4[(size_t)i * 4 * C4] = o;
    }
}

extern "C" void kernel_launch(void* const* d_in, const int* in_sizes, int n_in,
                              void* d_out, int out_size, void* d_ws, size_t ws_size,
                              hipStream_t stream) {
    const float* x  = (const float*)d_in[0];
    const float* w1 = (const float*)d_in[1];
    const float* w2 = (const float*)d_in[2];
    float* out = (float*)d_out;

    // workspace layout: part [B*CHUNKS*C]
    float* part = (float*)d_ws;

    gap_kernel       <<<dim3(CHUNKS, B), 256, 0, stream>>>(x, part);
    gate_scale_kernel<<<dim3(CHUNKS, B), 256, 0, stream>>>(x, part, w1, w2, out);
}